// Round 23
// baseline (277.572 us; speedup 1.0000x reference)
//
#include <hip/hip_runtime.h>

typedef unsigned short u16;
typedef unsigned int u32;
typedef __attribute__((ext_vector_type(8))) short bf16x8;   // 8 bf16 = 4 VGPRs
typedef __attribute__((ext_vector_type(4))) float f32x4;
typedef __bf16 bf16v8 __attribute__((ext_vector_type(8)));

// ---------- helpers ----------
__device__ __forceinline__ u16 f2bf(float x) {
  u32 u = __float_as_uint(x);
  u32 r = (u + 0x7FFFu + ((u >> 16) & 1u)) >> 16;   // RNE
  return (u16)r;
}
__device__ __forceinline__ float bf2f(u16 x) { return __uint_as_float(((u32)x) << 16); }

// Builtin MFMA (inline-asm had an unmodeled MFMA->VALU accumulator hazard).
__device__ __forceinline__ void mfma_bf16(f32x4& d, bf16x8 a, bf16x8 b) {
  d = __builtin_amdgcn_mfma_f32_16x16x32_bf16(
        __builtin_bit_cast(bf16v8, a), __builtin_bit_cast(bf16v8, b), d, 0, 0, 0);
}

__device__ __forceinline__ void gload16(const u16* g, u16* l) {
  __builtin_amdgcn_global_load_lds((const __attribute__((address_space(1))) u32*)g,
                                   (__attribute__((address_space(3))) u32*)l, 16, 0, 0);
}

__device__ __forceinline__ void store_c(u16* p, float v) { *p = f2bf(v); }
__device__ __forceinline__ void store_c(float* p, float v) { *p = v; }

// ---------- K1: fp32 -> bf16 convert (vectorized) ----------
__global__ void cvt4(const float* __restrict__ in, u16* __restrict__ out, int n4) {
  int i = blockIdx.x * 256 + threadIdx.x;
  if (i >= n4) return;
  float4 v = reinterpret_cast<const float4*>(in)[i];
  u32 lo = (u32)f2bf(v.x) | ((u32)f2bf(v.y) << 16);
  u32 hi = (u32)f2bf(v.z) | ((u32)f2bf(v.w) << 16);
  reinterpret_cast<uint2*>(out)[i] = make_uint2(lo, hi);
}

// ---------- K2: weight transpose+convert ----------
__global__ void wtrans3(const float* __restrict__ wq, const float* __restrict__ wk,
                        const float* __restrict__ wv,
                        u16* __restrict__ wqkt, u16* __restrict__ wvt) {
  const float* in; u16* out;
  switch (blockIdx.z) {
    case 0: in = wq; out = wqkt; break;
    case 1: in = wk; out = wqkt + (size_t)2048 * 2048; break;
    default: in = wv; out = wvt; break;
  }
  __shared__ float t[32][33];
  int n0 = blockIdx.x * 32, k0 = blockIdx.y * 32;
  int tx = threadIdx.x, ty = threadIdx.y;   // (32,8)
#pragma unroll
  for (int j = 0; j < 4; ++j)
    t[ty + 8 * j][tx] = in[(size_t)(k0 + ty + 8 * j) * 2048 + n0 + tx];
  __syncthreads();
#pragma unroll
  for (int j = 0; j < 4; ++j)
    out[(size_t)(n0 + ty + 8 * j) * 2048 + k0 + tx] = f2bf(t[tx][ty + 8 * j]);
}

__global__ void wtrans1(const float* __restrict__ in, u16* __restrict__ out) {
  __shared__ float t[32][33];
  int n0 = blockIdx.x * 32, k0 = blockIdx.y * 32;
  int tx = threadIdx.x, ty = threadIdx.y;   // (32,8)
#pragma unroll
  for (int j = 0; j < 4; ++j)
    t[ty + 8 * j][tx] = in[(size_t)(k0 + ty + 8 * j) * 2048 + n0 + tx];
  __syncthreads();
#pragma unroll
  for (int j = 0; j < 4; ++j)
    out[(size_t)(n0 + ty + 8 * j) * 2048 + k0 + tx] = f2bf(t[tx][ty + 8 * j]);
}

// ---------- K3: templated big-tile bf16 GEMM -- 2-tile regions over 4 buffers ----------
// r22: depth-3 was null for QK (84 us flat, MfmaUtil 34%) -> the cost is the
// per-K-step sync structure (m233: 2-barrier-per-step ~72% stage+vmcnt+bar
// overhead), not load latency. This round: process TWO K-tiles per barrier
// region over FOUR 32KB buffers -> sync events halve, and tile b's ds_reads
// overlap tile a's MFMAs inside the region (compiler emits fine lgkmcnt).
// Ledger (CH gloads/thread/stage): prologue stages 0..3 = 4CH outstanding;
// region top vmcnt(2CH) completes exactly tiles {a=tt, b=tt+1} (last region
// vmcnt(0)); region-end stages target buffers (tt+4)%4 = a%4 and
// (tt+5)%4 = b%4 -- both just freed by barrier-2. NT=64 (even) for all
// shapes. LDS: QK 128KB, V/out 96KB; all grids are 256 blocks = 1 block/CU.
template <int BM, int BN, int WM, int WN, typename CT>
__global__ __launch_bounds__(512, 2) void gemm256t(const u16* __restrict__ A,
                                                   const u16* __restrict__ Bt,
                                                   CT* __restrict__ C,
                                                   int M, int N, int K) {
  constexpr int MR = BM / WM / 16;
  constexpr int NR = BN / WN / 16;
  constexpr int CH = (BM + BN) / 128;         // gloads per thread per stage
  __shared__ u16 lds[4][(BM + BN) * 32];
  int tid = threadIdx.x;
  int lane = tid & 63, wave = tid >> 6;
  int g = lane >> 4, lr = lane & 15;
  int wr = wave / WN, wc = wave % WN;
  size_t brow = (size_t)blockIdx.y * BM, bcol = (size_t)blockIdx.x * BN;

  auto stage = [&](int kt, int bf) {
#pragma unroll
    for (int i = 0; i < CH; ++i) {
      int c = i * 512 + tid;
      bool isA = c < BM * 4;
      int p = isA ? c : c - BM * 4;
      int row = p >> 2, pc = p & 3;
      int lc = pc ^ ((row >> 1) & 3);         // inverse swizzle on source
      const u16* src = isA ? A  + (brow + row) * (size_t)K + kt + lc * 8
                           : Bt + (bcol + row) * (size_t)K + kt + lc * 8;
      gload16(src, &lds[bf][(isA ? 0 : BM * 32) + p * 8]);
    }
  };

  f32x4 acc[MR][NR];
#pragma unroll
  for (int m = 0; m < MR; ++m)
#pragma unroll
    for (int n = 0; n < NR; ++n) acc[m][n] = (f32x4){0.f, 0.f, 0.f, 0.f};

  int NT = K >> 5;                            // 64 for all shapes here (even)
  stage(0, 0);
  stage(32, 1);
  stage(64, 2);
  stage(96, 3);
  for (int tt = 0; tt < NT; tt += 2) {
    if (tt + 2 >= NT) asm volatile("s_waitcnt vmcnt(0)" ::: "memory");
    else              asm volatile("s_waitcnt vmcnt(%0)" :: "i"(2 * CH) : "memory");
    __builtin_amdgcn_s_barrier();             // raw: newer stages stay in flight
#pragma unroll
    for (int sub = 0; sub < 2; ++sub) {
      int buf = (tt + sub) & 3;
      const u16* La = &lds[buf][0];
      const u16* Lb = &lds[buf][BM * 32];
      __builtin_amdgcn_s_setprio(1);
      bf16x8 bfr[NR];
#pragma unroll
      for (int n = 0; n < NR; ++n) {
        int colr = wc * (BN / WN) + n * 16 + lr;
        bfr[n] = *(const bf16x8*)&Lb[colr * 32 + ((g ^ ((colr >> 1) & 3)) * 8)];
      }
#pragma unroll
      for (int m = 0; m < MR; ++m) {
        int rowr = wr * (BM / WM) + m * 16 + lr;
        bf16x8 afr = *(const bf16x8*)&La[rowr * 32 + ((g ^ ((rowr >> 1) & 3)) * 8)];
#pragma unroll
        for (int n = 0; n < NR; ++n) mfma_bf16(acc[m][n], afr, bfr[n]);
      }
      __builtin_amdgcn_s_setprio(0);
    }
    __builtin_amdgcn_s_barrier();             // all waves done with both bufs
    if (tt + 4 < NT) stage((tt + 4) * 32, (tt + 4) & 3);  // freed buffer a%4
    if (tt + 5 < NT) stage((tt + 5) * 32, (tt + 5) & 3);  // freed buffer b%4
  }
#pragma unroll
  for (int m = 0; m < MR; ++m)
#pragma unroll
    for (int n = 0; n < NR; ++n) {
      size_t row = brow + wr * (BM / WM) + m * 16 + 4 * g;
      size_t col = bcol + wc * (BN / WN) + n * 16 + lr;
#pragma unroll
      for (int r = 0; r < 4; ++r) store_c(&C[(row + r) * (size_t)N + col], acc[m][n][r]);
    }
}

// ---------- K4: RoPE in-place on fused QK buffer [bs][4096] ----------
__global__ void rope_kernel(u16* __restrict__ qk,
                            const float* __restrict__ sn, const float* __restrict__ cs) {
  int idx = blockIdx.x * 256 + threadIdx.x;   // < 2*2048*16*64
  int d = idx & 63;
  int h = (idx >> 6) & 15;
  int bs = idx >> 10;           // b*2048 + s
  int s = bs & 2047;
  size_t base = ((size_t)bs << 12) + h * 128;
  float c1 = cs[s * 128 + d], c2 = cs[s * 128 + d + 64];
  float s1 = sn[s * 128 + d], s2 = sn[s * 128 + d + 64];
  float q1 = bf2f(qk[base + d]), q2 = bf2f(qk[base + d + 64]);
  float k1 = bf2f(qk[base + 2048 + d]), k2 = bf2f(qk[base + 2048 + d + 64]);
  qk[base + d]      = f2bf(q1 * c1 - q2 * s1);
  qk[base + d + 64] = f2bf(q2 * c2 + q1 * s2);
  const float ks = 0.08838834764831845f;   // 128^-0.5
  qk[base + 2048 + d]      = f2bf((k1 * c1 - k2 * s1) * ks);
  qk[base + 2048 + d + 64] = f2bf((k2 * c2 + k1 * s2) * ks);
}

// ---------- K5: causal flash attention -- r15 depth-3 + XCD remap (r21/r22-validated) ----------
__global__ __launch_bounds__(512, 2) void attn(const u16* __restrict__ qk,
                                               const u16* __restrict__ vt,
                                               u16* __restrict__ y) {
  __shared__ u16 Ks[3][64 * 128];    // 16KB each
  __shared__ u16 Vs[3][128 * 64];    // 16KB each
  __shared__ u32 P_lds[8][16][33];   // per-wave P round-trip (32 data + pad)
  int tid = threadIdx.x;
  int wave = tid >> 6, lane = tid & 63;
  int g = lane >> 4, lr = lane & 15;
  int lin = blockIdx.x + 8 * blockIdx.y + 128 * blockIdx.z;   // 0..255
  int bxs = lin >> 5;            // supertile-pair index 0..7
  int h = lin & 15;
  int b = (lin >> 4) & 1;

  const u16* Q  = qk + ((size_t)b * 2048) * 4096 + h * 128;
  const u16* K  = qk + ((size_t)b * 2048) * 4096 + 2048 + h * 128;
  const u16* Vg = vt + (size_t)h * 128 * 4096 + (size_t)b * 2048;  // [d][s]
  u16* Y = y + ((size_t)b * 2048) * 2048 + h * 128;

  auto stage = [&](int kv0, int bf) {
#pragma unroll
    for (int i = 0; i < 2; ++i) {
      int c = tid + 512 * i;               // 0..1023
      int krow = c >> 4, kphys = (c & 15) << 4;     // K: 16 x 16B chunks/row
      gload16(K + (size_t)(kv0 + krow) * 4096 + ((kphys ^ ((krow & 7) << 4)) >> 1),
              &Ks[bf][c * 8]);
      int vrow = c >> 3, vphys = c & 7;             // V: 8 x 16B chunks/row
      gload16(Vg + (size_t)vrow * 4096 + kv0 + ((vphys ^ (vrow & 7)) * 8),
              &Vs[bf][c * 8]);
    }
  };

  for (int seg = 0; seg < 2; ++seg) {
    int sup = seg ? (15 - bxs) : bxs;
    int ntiles = 2 * sup + 2;        // kv-tiles of 64 covering kv <= sup*128+127
    int q0w = sup * 128 + wave * 16;

    bf16x8 qfr[4];
#pragma unroll
    for (int dc = 0; dc < 4; ++dc)
      qfr[dc] = *(const bf16x8*)&Q[(size_t)(q0w + lr) * 4096 + dc * 32 + g * 8];

    f32x4 o[8];
#pragma unroll
    for (int i = 0; i < 8; ++i) o[i] = (f32x4){0.f, 0.f, 0.f, 0.f};
    float lsum = 0.f;

    __syncthreads();                 // drains qfr + prior-seg readers/stores
    stage(0, 0);
    stage(64, 1);
    if (ntiles > 2) stage(128, 2);
    int buf = 0;
    for (int t = 0; t < ntiles; ++t) {
      int w = ntiles - 1 - t;
      if (w >= 2)      asm volatile("s_waitcnt vmcnt(8)" ::: "memory");
      else if (w == 1) asm volatile("s_waitcnt vmcnt(4)" ::: "memory");
      else             asm volatile("s_waitcnt vmcnt(0)" ::: "memory");
      __builtin_amdgcn_s_barrier();  // raw: loads for t+1,t+2 stay in flight
      int kv0 = t * 64;
      // ---- QK^T from swizzled Ks ----
      f32x4 st[4];
#pragma unroll
      for (int n = 0; n < 4; ++n) {
        f32x4 s4 = (f32x4){0.f, 0.f, 0.f, 0.f};
        int row = n * 16 + lr;
#pragma unroll
        for (int dc = 0; dc < 4; ++dc) {
          bf16x8 kfr = *(const bf16x8*)
              &Ks[buf][row * 128 + (((dc * 64 + 16 * g) ^ ((row & 7) << 4)) >> 1)];
          mfma_bf16(s4, kfr, qfr[dc]);   // A=K (row=kv), B=Q (col=q)
        }
        st[n] = s4;
      }
      // ---- masked exp (m==0), per-lane row-sum, pack to bf16 ----
      int qg = q0w + lr;
      u32 pk[8];
#pragma unroll
      for (int n = 0; n < 4; ++n)
#pragma unroll
        for (int rp = 0; rp < 2; ++rp) {
          int kvb = kv0 + n * 16 + 4 * g + rp * 2;
          float p0 = (kvb     <= qg) ? __expf(st[n][rp * 2])     : 0.f;
          float p1 = (kvb + 1 <= qg) ? __expf(st[n][rp * 2 + 1]) : 0.f;
          lsum += p0 + p1;
          pk[n * 2 + rp] = (u32)f2bf(p0) | ((u32)f2bf(p1) << 16);
        }
      // ---- P round-trip through per-wave LDS (u32 both ways; fenced) ----
#pragma unroll
      for (int n = 0; n < 4; ++n) {
        P_lds[wave][lr][8 * n + 2 * g]     = pk[n * 2];
        P_lds[wave][lr][8 * n + 2 * g + 1] = pk[n * 2 + 1];
      }
      asm volatile("" ::: "memory");
      // ---- PV from swizzled Vs, two k-halves ----
#pragma unroll
      for (int kh = 0; kh < 2; ++kh) {
        union { u32 w[4]; bf16x8 v; } pu;
#pragma unroll
        for (int j = 0; j < 4; ++j)
          pu.w[j] = P_lds[wave][lr][16 * kh + 4 * g + j];  // P[q=lr][kv=32kh+8g..]
        bf16x8 pf = pu.v;
#pragma unroll
        for (int dch = 0; dch < 8; ++dch) {
          int vr = dch * 16 + lr;
          bf16x8 vfr = *(const bf16x8*)
              &Vs[buf][vr * 64 + (((4 * kh + g) ^ (lr & 7)) * 8)];
          mfma_bf16(o[dch], pf, vfr);   // O[q=4g+r][d=dch*16+lr]
        }
      }
      __builtin_amdgcn_s_barrier();  // all waves done reading buf
      if (t + 3 < ntiles) stage((t + 3) * 64, buf);   // refill freed buffer
      buf = (buf == 2) ? 0 : buf + 1;
    }
    // ---- row-sum reduce + normalized store ----
    lsum += __shfl_xor(lsum, 16);
    lsum += __shfl_xor(lsum, 32);
    float linv[4];
#pragma unroll
    for (int r = 0; r < 4; ++r) linv[r] = 1.f / __shfl(lsum, 4 * g + r);
#pragma unroll
    for (int dch = 0; dch < 8; ++dch)
#pragma unroll
      for (int r = 0; r < 4; ++r)
        Y[(size_t)(q0w + 4 * g + r) * 2048 + dch * 16 + lr] = f2bf(o[dch][r] * linv[r]);
  }
}

// ---------- launch ----------
extern "C" void kernel_launch(void* const* d_in, const int* in_sizes, int n_in,
                              void* d_out, int out_size, void* d_ws, size_t ws_size,
                              hipStream_t stream) {
  const float* x  = (const float*)d_in[0];
  const float* wq = (const float*)d_in[1];
  const float* wk = (const float*)d_in[2];
  const float* wv = (const float*)d_in[3];
  const float* wo = (const float*)d_in[4];
  // d_in[5] = mask (unused; causal applied analytically)
  const float* sn = (const float*)d_in[6];
  const float* cs = (const float*)d_in[7];

  // workspace map (56 MiB total, proven):
  //   0        xb   (bf16 x, 16 MiB) -- reused as attention-out y
  //   16 MiB   wqkt (bf16 [wq^T; wk^T] stacked [4096][2048], 16 MiB)
  //   32 MiB   wvt  (bf16 wv^T, 8 MiB) -- reused for wo^T after V GEMM
  //   40 MiB   vt   (bf16 V^T [2048 d][4096 bs], 16 MiB)
  // Fused QK output [bs][4096] lives in d_out; overwritten by the final GEMM.
  char* W = (char*)d_ws;
  u16* xb   = (u16*)(W);
  u16* wqkt = (u16*)(W + (size_t)16 * 1024 * 1024);
  u16* wvt  = (u16*)(W + (size_t)32 * 1024 * 1024);
  u16* vt   = (u16*)(W + (size_t)40 * 1024 * 1024);
  u16* qkb  = (u16*)d_out;
  u16* yb   = xb;

  dim3 tb(32, 8);
  cvt4<<<8192, 256, 0, stream>>>(x, xb, 2097152);
  wtrans3<<<dim3(64, 64, 3), tb, 0, stream>>>(wq, wk, wv, wqkt, wvt);
  // fused [Q|K] = x @ [wq wk]  (M=4096, N=4096): 256x256, 256 blocks
  gemm256t<256, 256, 2, 4, u16><<<dim3(16, 16), 512, 0, stream>>>(
      xb, wqkt, qkb, 4096, 4096, 2048);
  // V^T = wv^T @ x^T  (M=2048, N=4096): 256x128 tiles -> 256 blocks
  gemm256t<256, 128, 4, 2, u16><<<dim3(32, 8), 512, 0, stream>>>(
      wvt, xb, vt, 2048, 4096, 2048);
  // wo^T -> wvt (wvt free after V GEMM)
  wtrans1<<<dim3(64, 64), tb, 0, stream>>>(wo, wvt);
  // RoPE in place on fused QK (K pre-scaled by H^-0.5)
  rope_kernel<<<16384, 256, 0, stream>>>(qkb, sn, cs);
  // mfma flash attention (r15 depth-3 + XCD-grouped remap) -> yb
  attn<<<dim3(8, 16, 2), 512, 0, stream>>>(qkb, vt, yb);
  // out = y @ wo  (M=4096, N=2048, f32 out): 128x256 tiles -> 256 blocks
  gemm256t<128, 256, 2, 4, float><<<dim3(8, 32), 512, 0, stream>>>(
      yb, wvt, (float*)d_out, 4096, 2048, 2048);
}

// Round 24
// 256.917 us; speedup vs baseline: 1.0804x; 1.0804x over previous
//
#include <hip/hip_runtime.h>

typedef unsigned short u16;
typedef unsigned int u32;
typedef __attribute__((ext_vector_type(8))) short bf16x8;   // 8 bf16 = 4 VGPRs
typedef __attribute__((ext_vector_type(4))) float f32x4;
typedef __bf16 bf16v8 __attribute__((ext_vector_type(8)));

// ---------- helpers ----------
__device__ __forceinline__ u16 f2bf(float x) {
  u32 u = __float_as_uint(x);
  u32 r = (u + 0x7FFFu + ((u >> 16) & 1u)) >> 16;   // RNE
  return (u16)r;
}
__device__ __forceinline__ float bf2f(u16 x) { return __uint_as_float(((u32)x) << 16); }

// Builtin MFMA (inline-asm had an unmodeled MFMA->VALU accumulator hazard).
__device__ __forceinline__ void mfma_bf16(f32x4& d, bf16x8 a, bf16x8 b) {
  d = __builtin_amdgcn_mfma_f32_16x16x32_bf16(
        __builtin_bit_cast(bf16v8, a), __builtin_bit_cast(bf16v8, b), d, 0, 0, 0);
}

__device__ __forceinline__ void gload16(const u16* g, u16* l) {
  __builtin_amdgcn_global_load_lds((const __attribute__((address_space(1))) u32*)g,
                                   (__attribute__((address_space(3))) u32*)l, 16, 0, 0);
}

__device__ __forceinline__ void store_c(u16* p, float v) { *p = f2bf(v); }
__device__ __forceinline__ void store_c(float* p, float v) { *p = v; }

// ---------- K1: fp32 -> bf16 convert (vectorized) ----------
__global__ void cvt4(const float* __restrict__ in, u16* __restrict__ out, int n4) {
  int i = blockIdx.x * 256 + threadIdx.x;
  if (i >= n4) return;
  float4 v = reinterpret_cast<const float4*>(in)[i];
  u32 lo = (u32)f2bf(v.x) | ((u32)f2bf(v.y) << 16);
  u32 hi = (u32)f2bf(v.z) | ((u32)f2bf(v.w) << 16);
  reinterpret_cast<uint2*>(out)[i] = make_uint2(lo, hi);
}

// ---------- K2: weight transpose+convert ----------
__global__ void wtrans3(const float* __restrict__ wq, const float* __restrict__ wk,
                        const float* __restrict__ wv,
                        u16* __restrict__ wqkt, u16* __restrict__ wvt) {
  const float* in; u16* out;
  switch (blockIdx.z) {
    case 0: in = wq; out = wqkt; break;
    case 1: in = wk; out = wqkt + (size_t)2048 * 2048; break;
    default: in = wv; out = wvt; break;
  }
  __shared__ float t[32][33];
  int n0 = blockIdx.x * 32, k0 = blockIdx.y * 32;
  int tx = threadIdx.x, ty = threadIdx.y;   // (32,8)
#pragma unroll
  for (int j = 0; j < 4; ++j)
    t[ty + 8 * j][tx] = in[(size_t)(k0 + ty + 8 * j) * 2048 + n0 + tx];
  __syncthreads();
#pragma unroll
  for (int j = 0; j < 4; ++j)
    out[(size_t)(n0 + ty + 8 * j) * 2048 + k0 + tx] = f2bf(t[tx][ty + 8 * j]);
}

__global__ void wtrans1(const float* __restrict__ in, u16* __restrict__ out) {
  __shared__ float t[32][33];
  int n0 = blockIdx.x * 32, k0 = blockIdx.y * 32;
  int tx = threadIdx.x, ty = threadIdx.y;   // (32,8)
#pragma unroll
  for (int j = 0; j < 4; ++j)
    t[ty + 8 * j][tx] = in[(size_t)(k0 + ty + 8 * j) * 2048 + n0 + tx];
  __syncthreads();
#pragma unroll
  for (int j = 0; j < 4; ++j)
    out[(size_t)(n0 + ty + 8 * j) * 2048 + k0 + tx] = f2bf(t[tx][ty + 8 * j]);
}

// ---------- K3: templated big-tile bf16 GEMM, DEPTH-3 counted-vmcnt pipeline ----------
// r22 champion config. r23's 2-tile-region variant regressed (QK 84->94us,
// MfmaUtil 34->29.5) -- confirms m196: coarse phase-split without the fine
// per-phase interleave hurts. The 2-barrier depth-3 structure stands as the
// session's validated GEMM template.
// Ledger: prologue stages 0,1,2 = 3*CH outstanding; steady vmcnt(2*CH)
// completes exactly tile t (t+1,t+2 in flight); tail vmcnt(CH)/vmcnt(0);
// refill buffer t%3 after the compute barrier.
template <int BM, int BN, int WM, int WN, typename CT>
__global__ __launch_bounds__(512, 2) void gemm256t(const u16* __restrict__ A,
                                                   const u16* __restrict__ Bt,
                                                   CT* __restrict__ C,
                                                   int M, int N, int K) {
  constexpr int MR = BM / WM / 16;
  constexpr int NR = BN / WN / 16;
  constexpr int CH = (BM + BN) / 128;         // gloads per thread per stage
  __shared__ u16 lds[3][(BM + BN) * 32];
  int tid = threadIdx.x;
  int lane = tid & 63, wave = tid >> 6;
  int g = lane >> 4, lr = lane & 15;
  int wr = wave / WN, wc = wave % WN;
  size_t brow = (size_t)blockIdx.y * BM, bcol = (size_t)blockIdx.x * BN;

  auto stage = [&](int kt, int bf) {
#pragma unroll
    for (int i = 0; i < CH; ++i) {
      int c = i * 512 + tid;
      bool isA = c < BM * 4;
      int p = isA ? c : c - BM * 4;
      int row = p >> 2, pc = p & 3;
      int lc = pc ^ ((row >> 1) & 3);         // inverse swizzle on source
      const u16* src = isA ? A  + (brow + row) * (size_t)K + kt + lc * 8
                           : Bt + (bcol + row) * (size_t)K + kt + lc * 8;
      gload16(src, &lds[bf][(isA ? 0 : BM * 32) + p * 8]);
    }
  };

  f32x4 acc[MR][NR];
#pragma unroll
  for (int m = 0; m < MR; ++m)
#pragma unroll
    for (int n = 0; n < NR; ++n) acc[m][n] = (f32x4){0.f, 0.f, 0.f, 0.f};

  int NT = K >> 5;                            // = 64 for all shapes here
  stage(0, 0);
  stage(32, 1);
  stage(64, 2);
  int buf = 0;
  for (int t = 0; t < NT; ++t) {
    int w = NT - 1 - t;
    if (w >= 2)      asm volatile("s_waitcnt vmcnt(%0)" :: "i"(2 * CH) : "memory");
    else if (w == 1) asm volatile("s_waitcnt vmcnt(%0)" :: "i"(CH) : "memory");
    else             asm volatile("s_waitcnt vmcnt(0)" ::: "memory");
    __builtin_amdgcn_s_barrier();             // raw: t+1,t+2 stay in flight
    const u16* La = &lds[buf][0];
    const u16* Lb = &lds[buf][BM * 32];
    __builtin_amdgcn_s_setprio(1);
    bf16x8 bfr[NR];
#pragma unroll
    for (int n = 0; n < NR; ++n) {
      int colr = wc * (BN / WN) + n * 16 + lr;
      bfr[n] = *(const bf16x8*)&Lb[colr * 32 + ((g ^ ((colr >> 1) & 3)) * 8)];
    }
#pragma unroll
    for (int m = 0; m < MR; ++m) {
      int rowr = wr * (BM / WM) + m * 16 + lr;
      bf16x8 afr = *(const bf16x8*)&La[rowr * 32 + ((g ^ ((rowr >> 1) & 3)) * 8)];
#pragma unroll
      for (int n = 0; n < NR; ++n) mfma_bf16(acc[m][n], afr, bfr[n]);
    }
    __builtin_amdgcn_s_setprio(0);
    __builtin_amdgcn_s_barrier();             // all waves done reading lds[buf]
    if (t + 3 < NT) stage((t + 3) * 32, buf); // refill freed buffer; in flight
    buf = (buf == 2) ? 0 : buf + 1;
  }
#pragma unroll
  for (int m = 0; m < MR; ++m)
#pragma unroll
    for (int n = 0; n < NR; ++n) {
      size_t row = brow + wr * (BM / WM) + m * 16 + 4 * g;
      size_t col = bcol + wc * (BN / WN) + n * 16 + lr;
#pragma unroll
      for (int r = 0; r < 4; ++r) store_c(&C[(row + r) * (size_t)N + col], acc[m][n][r]);
    }
}

// ---------- K4: RoPE in-place on fused QK buffer [bs][4096] ----------
__global__ void rope_kernel(u16* __restrict__ qk,
                            const float* __restrict__ sn, const float* __restrict__ cs) {
  int idx = blockIdx.x * 256 + threadIdx.x;   // < 2*2048*16*64
  int d = idx & 63;
  int h = (idx >> 6) & 15;
  int bs = idx >> 10;           // b*2048 + s
  int s = bs & 2047;
  size_t base = ((size_t)bs << 12) + h * 128;
  float c1 = cs[s * 128 + d], c2 = cs[s * 128 + d + 64];
  float s1 = sn[s * 128 + d], s2 = sn[s * 128 + d + 64];
  float q1 = bf2f(qk[base + d]), q2 = bf2f(qk[base + d + 64]);
  float k1 = bf2f(qk[base + 2048 + d]), k2 = bf2f(qk[base + 2048 + d + 64]);
  qk[base + d]      = f2bf(q1 * c1 - q2 * s1);
  qk[base + d + 64] = f2bf(q2 * c2 + q1 * s2);
  const float ks = 0.08838834764831845f;   // 128^-0.5
  qk[base + 2048 + d]      = f2bf((k1 * c1 - k2 * s1) * ks);
  qk[base + 2048 + d + 64] = f2bf((k2 * c2 + k1 * s2) * ks);
}

// ---------- K5: causal flash attention -- r15 depth-3 + XCD remap (r21/r22-validated) ----------
__global__ __launch_bounds__(512, 2) void attn(const u16* __restrict__ qk,
                                               const u16* __restrict__ vt,
                                               u16* __restrict__ y) {
  __shared__ u16 Ks[3][64 * 128];    // 16KB each
  __shared__ u16 Vs[3][128 * 64];    // 16KB each
  __shared__ u32 P_lds[8][16][33];   // per-wave P round-trip (32 data + pad)
  int tid = threadIdx.x;
  int wave = tid >> 6, lane = tid & 63;
  int g = lane >> 4, lr = lane & 15;
  int lin = blockIdx.x + 8 * blockIdx.y + 128 * blockIdx.z;   // 0..255
  int bxs = lin >> 5;            // supertile-pair index 0..7
  int h = lin & 15;
  int b = (lin >> 4) & 1;

  const u16* Q  = qk + ((size_t)b * 2048) * 4096 + h * 128;
  const u16* K  = qk + ((size_t)b * 2048) * 4096 + 2048 + h * 128;
  const u16* Vg = vt + (size_t)h * 128 * 4096 + (size_t)b * 2048;  // [d][s]
  u16* Y = y + ((size_t)b * 2048) * 2048 + h * 128;

  auto stage = [&](int kv0, int bf) {
#pragma unroll
    for (int i = 0; i < 2; ++i) {
      int c = tid + 512 * i;               // 0..1023
      int krow = c >> 4, kphys = (c & 15) << 4;     // K: 16 x 16B chunks/row
      gload16(K + (size_t)(kv0 + krow) * 4096 + ((kphys ^ ((krow & 7) << 4)) >> 1),
              &Ks[bf][c * 8]);
      int vrow = c >> 3, vphys = c & 7;             // V: 8 x 16B chunks/row
      gload16(Vg + (size_t)vrow * 4096 + kv0 + ((vphys ^ (vrow & 7)) * 8),
              &Vs[bf][c * 8]);
    }
  };

  for (int seg = 0; seg < 2; ++seg) {
    int sup = seg ? (15 - bxs) : bxs;
    int ntiles = 2 * sup + 2;        // kv-tiles of 64 covering kv <= sup*128+127
    int q0w = sup * 128 + wave * 16;

    bf16x8 qfr[4];
#pragma unroll
    for (int dc = 0; dc < 4; ++dc)
      qfr[dc] = *(const bf16x8*)&Q[(size_t)(q0w + lr) * 4096 + dc * 32 + g * 8];

    f32x4 o[8];
#pragma unroll
    for (int i = 0; i < 8; ++i) o[i] = (f32x4){0.f, 0.f, 0.f, 0.f};
    float lsum = 0.f;

    __syncthreads();                 // drains qfr + prior-seg readers/stores
    stage(0, 0);
    stage(64, 1);
    if (ntiles > 2) stage(128, 2);
    int buf = 0;
    for (int t = 0; t < ntiles; ++t) {
      int w = ntiles - 1 - t;
      if (w >= 2)      asm volatile("s_waitcnt vmcnt(8)" ::: "memory");
      else if (w == 1) asm volatile("s_waitcnt vmcnt(4)" ::: "memory");
      else             asm volatile("s_waitcnt vmcnt(0)" ::: "memory");
      __builtin_amdgcn_s_barrier();  // raw: loads for t+1,t+2 stay in flight
      int kv0 = t * 64;
      // ---- QK^T from swizzled Ks ----
      f32x4 st[4];
#pragma unroll
      for (int n = 0; n < 4; ++n) {
        f32x4 s4 = (f32x4){0.f, 0.f, 0.f, 0.f};
        int row = n * 16 + lr;
#pragma unroll
        for (int dc = 0; dc < 4; ++dc) {
          bf16x8 kfr = *(const bf16x8*)
              &Ks[buf][row * 128 + (((dc * 64 + 16 * g) ^ ((row & 7) << 4)) >> 1)];
          mfma_bf16(s4, kfr, qfr[dc]);   // A=K (row=kv), B=Q (col=q)
        }
        st[n] = s4;
      }
      // ---- masked exp (m==0), per-lane row-sum, pack to bf16 ----
      int qg = q0w + lr;
      u32 pk[8];
#pragma unroll
      for (int n = 0; n < 4; ++n)
#pragma unroll
        for (int rp = 0; rp < 2; ++rp) {
          int kvb = kv0 + n * 16 + 4 * g + rp * 2;
          float p0 = (kvb     <= qg) ? __expf(st[n][rp * 2])     : 0.f;
          float p1 = (kvb + 1 <= qg) ? __expf(st[n][rp * 2 + 1]) : 0.f;
          lsum += p0 + p1;
          pk[n * 2 + rp] = (u32)f2bf(p0) | ((u32)f2bf(p1) << 16);
        }
      // ---- P round-trip through per-wave LDS (u32 both ways; fenced) ----
#pragma unroll
      for (int n = 0; n < 4; ++n) {
        P_lds[wave][lr][8 * n + 2 * g]     = pk[n * 2];
        P_lds[wave][lr][8 * n + 2 * g + 1] = pk[n * 2 + 1];
      }
      asm volatile("" ::: "memory");
      // ---- PV from swizzled Vs, two k-halves ----
#pragma unroll
      for (int kh = 0; kh < 2; ++kh) {
        union { u32 w[4]; bf16x8 v; } pu;
#pragma unroll
        for (int j = 0; j < 4; ++j)
          pu.w[j] = P_lds[wave][lr][16 * kh + 4 * g + j];  // P[q=lr][kv=32kh+8g..]
        bf16x8 pf = pu.v;
#pragma unroll
        for (int dch = 0; dch < 8; ++dch) {
          int vr = dch * 16 + lr;
          bf16x8 vfr = *(const bf16x8*)
              &Vs[buf][vr * 64 + (((4 * kh + g) ^ (lr & 7)) * 8)];
          mfma_bf16(o[dch], pf, vfr);   // O[q=4g+r][d=dch*16+lr]
        }
      }
      __builtin_amdgcn_s_barrier();  // all waves done reading buf
      if (t + 3 < ntiles) stage((t + 3) * 64, buf);   // refill freed buffer
      buf = (buf == 2) ? 0 : buf + 1;
    }
    // ---- row-sum reduce + normalized store ----
    lsum += __shfl_xor(lsum, 16);
    lsum += __shfl_xor(lsum, 32);
    float linv[4];
#pragma unroll
    for (int r = 0; r < 4; ++r) linv[r] = 1.f / __shfl(lsum, 4 * g + r);
#pragma unroll
    for (int dch = 0; dch < 8; ++dch)
#pragma unroll
      for (int r = 0; r < 4; ++r)
        Y[(size_t)(q0w + 4 * g + r) * 2048 + dch * 16 + lr] = f2bf(o[dch][r] * linv[r]);
  }
}

// ---------- launch ----------
extern "C" void kernel_launch(void* const* d_in, const int* in_sizes, int n_in,
                              void* d_out, int out_size, void* d_ws, size_t ws_size,
                              hipStream_t stream) {
  const float* x  = (const float*)d_in[0];
  const float* wq = (const float*)d_in[1];
  const float* wk = (const float*)d_in[2];
  const float* wv = (const float*)d_in[3];
  const float* wo = (const float*)d_in[4];
  // d_in[5] = mask (unused; causal applied analytically)
  const float* sn = (const float*)d_in[6];
  const float* cs = (const float*)d_in[7];

  // workspace map (56 MiB total, proven):
  //   0        xb   (bf16 x, 16 MiB) -- reused as attention-out y
  //   16 MiB   wqkt (bf16 [wq^T; wk^T] stacked [4096][2048], 16 MiB)
  //   32 MiB   wvt  (bf16 wv^T, 8 MiB) -- reused for wo^T after V GEMM
  //   40 MiB   vt   (bf16 V^T [2048 d][4096 bs], 16 MiB)
  // Fused QK output [bs][4096] lives in d_out; overwritten by the final GEMM.
  char* W = (char*)d_ws;
  u16* xb   = (u16*)(W);
  u16* wqkt = (u16*)(W + (size_t)16 * 1024 * 1024);
  u16* wvt  = (u16*)(W + (size_t)32 * 1024 * 1024);
  u16* vt   = (u16*)(W + (size_t)40 * 1024 * 1024);
  u16* qkb  = (u16*)d_out;
  u16* yb   = xb;

  dim3 tb(32, 8);
  cvt4<<<8192, 256, 0, stream>>>(x, xb, 2097152);
  wtrans3<<<dim3(64, 64, 3), tb, 0, stream>>>(wq, wk, wv, wqkt, wvt);
  // fused [Q|K] = x @ [wq wk]  (M=4096, N=4096): 256x256, 256 blocks
  gemm256t<256, 256, 2, 4, u16><<<dim3(16, 16), 512, 0, stream>>>(
      xb, wqkt, qkb, 4096, 4096, 2048);
  // V^T = wv^T @ x^T  (M=2048, N=4096): 256x128 tiles -> 256 blocks
  gemm256t<256, 128, 4, 2, u16><<<dim3(32, 8), 512, 0, stream>>>(
      wvt, xb, vt, 2048, 4096, 2048);
  // wo^T -> wvt (wvt free after V GEMM)
  wtrans1<<<dim3(64, 64), tb, 0, stream>>>(wo, wvt);
  // RoPE in place on fused QK (K pre-scaled by H^-0.5)
  rope_kernel<<<16384, 256, 0, stream>>>(qkb, sn, cs);
  // mfma flash attention (r15 depth-3 + XCD-grouped remap) -> yb
  attn<<<dim3(8, 16, 2), 512, 0, stream>>>(qkb, vt, yb);
  // out = y @ wo  (M=4096, N=2048, f32 out): 128x256 tiles -> 256 blocks
  gemm256t<128, 256, 2, 4, float><<<dim3(8, 32), 512, 0, stream>>>(
      yb, wvt, (float*)d_out, 4096, 2048, 2048);
}